// Round 1
// baseline (29.489 us; speedup 1.0000x reference)
//
#include <hip/hip_runtime.h>
#include <cstdint>
#include <cstddef>

typedef _Float16 half8 __attribute__((ext_vector_type(8)));
typedef float f32x4 __attribute__((ext_vector_type(4)));
typedef float float4v __attribute__((ext_vector_type(4)));

static constexpr int kN = 256;           // state dim (N == K)
static constexpr int kKSteps = kN / 32;  // 8 k-steps of 32
static constexpr int kNT = kN / 16;      // 16 n-tiles
static constexpr int kBM = 64;           // rows per block (4 waves x 16)

// Pack A_stacked[t] (fp32 row-major [n][k]) into f16 MFMA B-fragment order:
// a16[((nt*8 + ks)*64 + lane)*8 + j] = A[nt*16 + (lane&15)][ks*32 + (lane>>4)*8 + j]
// so a wave's b-frag load for (nt,ks) is 64 lanes x 16B fully coalesced.
__global__ __launch_bounds__(256) void hippo_prep(
    const float* __restrict__ A_stacked, const int* __restrict__ tptr,
    _Float16* __restrict__ a16)
{
    const int t = tptr[0];
    const float* __restrict__ A = A_stacked + (size_t)t * kN * kN;
    const int tid = blockIdx.x * 256 + threadIdx.x;   // 0..8191
    const int nt = tid >> 9;
    const int ks = (tid >> 6) & 7;
    const int l  = tid & 63;
    const int row = nt * 16 + (l & 15);
    const int k0  = ks * 32 + ((l >> 4) << 3);
    const float* __restrict__ src = A + row * kN + k0;
    float4v v0 = *(const float4v*)(src);
    float4v v1 = *(const float4v*)(src + 4);
    half8 h;
    h[0] = (_Float16)v0[0]; h[1] = (_Float16)v0[1];
    h[2] = (_Float16)v0[2]; h[3] = (_Float16)v0[3];
    h[4] = (_Float16)v1[0]; h[5] = (_Float16)v1[1];
    h[6] = (_Float16)v1[2]; h[7] = (_Float16)v1[3];
    ((half8*)a16)[tid] = h;
}

// out[m][n] = sum_k c[m][k] * A[n][k] + b[n] * f[m]
// Each wave: one 16-row m-tile x all 256 cols (16 n-tiles). 4 waves/block -> BM=64.
__global__ __launch_bounds__(256) void hippo_gemm(
    const float* __restrict__ c, const float* __restrict__ f,
    const float* __restrict__ Bst, const int* __restrict__ tptr,
    const _Float16* __restrict__ a16, float* __restrict__ out)
{
    const int tid  = threadIdx.x;
    const int l    = tid & 63;
    const int wid  = tid >> 6;                 // 0..3
    const int m0   = blockIdx.x * kBM + wid * 16;
    const int lo16 = l & 15;
    const int hi4  = l >> 4;

    // A-operand (c) fragment source: lane reads c[m0+(l&15)][ks*32 + (l>>4)*8 .. +8]
    const float* __restrict__ cptr = c + (size_t)(m0 + lo16) * kN + (hi4 << 3);

    f32x4 acc[kNT];
    #pragma unroll
    for (int i = 0; i < kNT; ++i) acc[i] = (f32x4){0.f, 0.f, 0.f, 0.f};

    const half8* __restrict__ a16v = (const half8*)a16;

    for (int ks = 0; ks < kKSteps; ++ks) {
        float4v v0 = *(const float4v*)(cptr + ks * 32);
        float4v v1 = *(const float4v*)(cptr + ks * 32 + 4);
        half8 afrag;
        afrag[0] = (_Float16)v0[0]; afrag[1] = (_Float16)v0[1];
        afrag[2] = (_Float16)v0[2]; afrag[3] = (_Float16)v0[3];
        afrag[4] = (_Float16)v1[0]; afrag[5] = (_Float16)v1[1];
        afrag[6] = (_Float16)v1[2]; afrag[7] = (_Float16)v1[3];
        #pragma unroll
        for (int nt = 0; nt < kNT; ++nt) {
            half8 bfrag = a16v[(nt * kKSteps + ks) * 64 + l];
            acc[nt] = __builtin_amdgcn_mfma_f32_16x16x32_f16(afrag, bfrag, acc[nt], 0, 0, 0);
        }
    }

    // Epilogue: out[row][col] = acc + b[col]*f[row]
    const int t = tptr[0];
    const float* __restrict__ brow = Bst + (size_t)t * kN;
    float fv[4];
    #pragma unroll
    for (int r = 0; r < 4; ++r) fv[r] = f[m0 + (hi4 << 2) + r];

    #pragma unroll
    for (int nt = 0; nt < kNT; ++nt) {
        const int col = nt * 16 + lo16;
        const float bv = brow[col];
        #pragma unroll
        for (int r = 0; r < 4; ++r) {
            const int row = m0 + (hi4 << 2) + r;
            out[(size_t)row * kN + col] = acc[nt][r] + bv * fv[r];
        }
    }
}

extern "C" void kernel_launch(void* const* d_in, const int* in_sizes, int n_in,
                              void* d_out, int out_size, void* d_ws, size_t ws_size,
                              hipStream_t stream) {
    const float* c   = (const float*)d_in[0];
    const float* f   = (const float*)d_in[1];
    const float* A   = (const float*)d_in[2];
    const float* B   = (const float*)d_in[3];
    const int*   t   = (const int*)d_in[4];
    float* out = (float*)d_out;
    _Float16* a16 = (_Float16*)d_ws;   // 128 KiB packed A[t] in f16

    const int batch = in_sizes[0] / kN;   // 32768

    hipLaunchKernelGGL(hippo_prep, dim3(32), dim3(256), 0, stream, A, t, a16);
    hipLaunchKernelGGL(hippo_gemm, dim3(batch / kBM), dim3(256), 0, stream,
                       c, f, B, t, a16, out);
}

// Round 2
// 25.804 us; speedup vs baseline: 1.1428x; 1.1428x over previous
//
#include <hip/hip_runtime.h>
#include <cstdint>
#include <cstddef>

typedef _Float16 half8 __attribute__((ext_vector_type(8)));
typedef float f32x4 __attribute__((ext_vector_type(4)));
typedef float float4v __attribute__((ext_vector_type(4)));

static constexpr int kN = 256;           // state dim (N == K)
static constexpr int kKSteps = kN / 32;  // 8 k-steps of 32
static constexpr int kNT = kN / 16;      // 16 n-tiles
static constexpr int kWaves = 8;         // waves per block
static constexpr int kBM = kWaves * 16;  // 128 rows per block
static constexpr size_t kABytes = (size_t)kN * kN * 2;  // 128 KiB packed f16 A

// Pack A_stacked[t] (fp32 row-major [n][k]) into f16 MFMA B-fragment order:
// a16[((nt*8 + ks)*64 + lane)*8 + j] = A[nt*16 + (lane&15)][ks*32 + (lane>>4)*8 + j]
__global__ __launch_bounds__(256) void hippo_prep(
    const float* __restrict__ A_stacked, const int* __restrict__ tptr,
    _Float16* __restrict__ a16)
{
    const int t = tptr[0];
    const float* __restrict__ A = A_stacked + (size_t)t * kN * kN;
    const int tid = blockIdx.x * 256 + threadIdx.x;   // 0..8191
    const int nt = tid >> 9;
    const int ks = (tid >> 6) & 7;
    const int l  = tid & 63;
    const int row = nt * 16 + (l & 15);
    const int k0  = ks * 32 + ((l >> 4) << 3);
    const float* __restrict__ src = A + row * kN + k0;
    float4v v0 = *(const float4v*)(src);
    float4v v1 = *(const float4v*)(src + 4);
    half8 h;
    h[0] = (_Float16)v0[0]; h[1] = (_Float16)v0[1];
    h[2] = (_Float16)v0[2]; h[3] = (_Float16)v0[3];
    h[4] = (_Float16)v1[0]; h[5] = (_Float16)v1[1];
    h[6] = (_Float16)v1[2]; h[7] = (_Float16)v1[3];
    ((half8*)a16)[tid] = h;
}

// out[m][n] = sum_k c[m][k] * A[n][k] + b[n] * f[m]
// 8 waves/block, each wave: 16 rows x 256 cols. B-frags from LDS, c bulk-prefetched.
__global__ __launch_bounds__(512, 2) void hippo_gemm(
    const float* __restrict__ c, const float* __restrict__ f,
    const float* __restrict__ Bst, const int* __restrict__ tptr,
    const _Float16* __restrict__ a16, float* __restrict__ out)
{
    extern __shared__ char lds_raw[];
    _Float16* __restrict__ As = (_Float16*)lds_raw;   // frag-linear copy of a16

    const int tid  = threadIdx.x;
    const int l    = tid & 63;
    const int wid  = tid >> 6;                 // 0..7
    const int m0   = blockIdx.x * kBM + wid * 16;
    const int lo16 = l & 15;
    const int hi4  = l >> 4;

    // ---- issue bulk c prefetch (16 dwordx4 per lane, HBM) ----
    const float* __restrict__ cptr = c + (size_t)(m0 + lo16) * kN + (hi4 << 3);
    f32x4 cv[2 * kKSteps];
    #pragma unroll
    for (int ks = 0; ks < kKSteps; ++ks) {
        cv[2 * ks]     = *(const float4v*)(cptr + ks * 32);
        cv[2 * ks + 1] = *(const float4v*)(cptr + ks * 32 + 4);
    }

    // ---- stage packed A into LDS (128 KiB), linear, global_load_lds x16 ----
    // chunk = 1 KiB per wave-call; wave wid handles chunks {i*kWaves + wid}.
    {
        const char* __restrict__ gbase = (const char*)a16;
        char* __restrict__ lbase = lds_raw;
        #pragma unroll
        for (int i = 0; i < 16; ++i) {
            const int chunk = i * kWaves + wid;          // 0..127
            const size_t off = (size_t)chunk * 1024 + (size_t)l * 16;
            __builtin_amdgcn_global_load_lds(
                (const __attribute__((address_space(1))) void*)(gbase + off),
                (__attribute__((address_space(3))) void*)(lbase + off),
                16, 0, 0);
        }
    }
    __syncthreads();   // waits vmcnt(0): LDS staged AND all c-loads landed

    // ---- main loop: 8 k-steps x 16 n-tiles, B from LDS ----
    f32x4 acc[kNT];
    #pragma unroll
    for (int i = 0; i < kNT; ++i) acc[i] = (f32x4){0.f, 0.f, 0.f, 0.f};

    const half8* __restrict__ Bs = (const half8*)As;

    #pragma unroll
    for (int ks = 0; ks < kKSteps; ++ks) {
        half8 af;
        f32x4 v0 = cv[2 * ks], v1 = cv[2 * ks + 1];
        af[0] = (_Float16)v0[0]; af[1] = (_Float16)v0[1];
        af[2] = (_Float16)v0[2]; af[3] = (_Float16)v0[3];
        af[4] = (_Float16)v1[0]; af[5] = (_Float16)v1[1];
        af[6] = (_Float16)v1[2]; af[7] = (_Float16)v1[3];
        #pragma unroll
        for (int nt = 0; nt < kNT; ++nt) {
            half8 bf = Bs[(nt * kKSteps + ks) * 64 + l];
            acc[nt] = __builtin_amdgcn_mfma_f32_16x16x32_f16(af, bf, acc[nt], 0, 0, 0);
        }
    }

    // ---- epilogue: out[row][col] = acc + b[col]*f[row] ----
    const int t = tptr[0];
    const float* __restrict__ brow = Bst + (size_t)t * kN;
    float fv[4];
    #pragma unroll
    for (int r = 0; r < 4; ++r) fv[r] = f[m0 + (hi4 << 2) + r];

    #pragma unroll
    for (int nt = 0; nt < kNT; ++nt) {
        const int col = nt * 16 + lo16;
        const float bv = brow[col];
        #pragma unroll
        for (int r = 0; r < 4; ++r) {
            const int row = m0 + (hi4 << 2) + r;
            out[(size_t)row * kN + col] = acc[nt][r] + bv * fv[r];
        }
    }
}

extern "C" void kernel_launch(void* const* d_in, const int* in_sizes, int n_in,
                              void* d_out, int out_size, void* d_ws, size_t ws_size,
                              hipStream_t stream) {
    const float* c   = (const float*)d_in[0];
    const float* f   = (const float*)d_in[1];
    const float* A   = (const float*)d_in[2];
    const float* B   = (const float*)d_in[3];
    const int*   t   = (const int*)d_in[4];
    float* out = (float*)d_out;
    _Float16* a16 = (_Float16*)d_ws;   // 128 KiB packed A[t] in f16

    const int batch = in_sizes[0] / kN;   // 32768

    static bool attr_set = false;
    (void)attr_set;
    hipFuncSetAttribute((const void*)hippo_gemm,
                        hipFuncAttributeMaxDynamicSharedMemorySize,
                        (int)kABytes);

    hipLaunchKernelGGL(hippo_prep, dim3(32), dim3(256), 0, stream, A, t, a16);
    hipLaunchKernelGGL(hippo_gemm, dim3(batch / kBM), dim3(512), kABytes, stream,
                       c, f, B, t, a16, out);
}

// Round 3
// 24.435 us; speedup vs baseline: 1.2068x; 1.0560x over previous
//
#include <hip/hip_runtime.h>
#include <cstdint>
#include <cstddef>

typedef _Float16 half8 __attribute__((ext_vector_type(8)));
typedef float f32x4 __attribute__((ext_vector_type(4)));

static constexpr int kN  = 256;          // state dim (N == K)
static constexpr int kKS = 8;            // k-steps of 32
static constexpr int kNT = 16;           // n-tiles of 16
static constexpr int kWaves = 8;         // waves per block
static constexpr int kBM = kWaves * 16;  // 128 rows per block
static constexpr size_t kLDS = (size_t)kN * kN * 2;  // 128 KiB packed f16 A

// Single fused kernel:
//   out[m][n] = sum_k c[m][k] * A_t[n][k] + b[n] * f[m]
// Each block (512 thr, 8 waves) packs A_t -> LDS f16 frag layout, then each
// wave computes a 16-row x 256-col slab. nt-outer loop streams stores during
// MFMA so the write BW overlaps compute.
__global__ __launch_bounds__(512, 2) void hippo_fused(
    const float* __restrict__ c, const float* __restrict__ f,
    const float* __restrict__ A_stacked, const float* __restrict__ Bst,
    const int* __restrict__ tptr, float* __restrict__ out)
{
    extern __shared__ char lds_raw[];
    _Float16* __restrict__ As = (_Float16*)lds_raw;

    const int tid  = threadIdx.x;
    const int l    = tid & 63;
    const int wid  = tid >> 6;          // 0..7
    const int lo16 = l & 15;
    const int hi4  = l >> 4;
    const int t    = tptr[0];

    // ---- A-pack loads FIRST (L2/L3-resident broadcast; oldest in VMEM queue)
    // thread (wid,l) handles frag units (nt=u, ks=wid, lane=l), u = 0..15:
    //   reads A_t[u*16 + lo16][wid*32 + hi4*8 .. +8]  (32 B)
    //   LDS dest byte offset (u*512 + tid)*16  -> frag-linear, conflict-free
    const float* __restrict__ asrc =
        A_stacked + (size_t)t * kN * kN + (size_t)lo16 * kN + wid * 32 + (hi4 << 3);
    f32x4 a0[kNT], a1[kNT];
    #pragma unroll
    for (int u = 0; u < kNT; ++u) {
        const float* p = asrc + (size_t)u * 16 * kN;
        a0[u] = *(const f32x4*)p;
        a1[u] = *(const f32x4*)(p + 4);
    }

    // ---- c prefetch (HBM): lane reads c[m0+lo16][ks*32 + hi4*8 .. +8]
    const int m0 = blockIdx.x * kBM + wid * 16;
    const float* __restrict__ cptr = c + (size_t)(m0 + lo16) * kN + (hi4 << 3);
    f32x4 cv0[kKS], cv1[kKS];
    #pragma unroll
    for (int ks = 0; ks < kKS; ++ks) {
        cv0[ks] = *(const f32x4*)(cptr + ks * 32);
        cv1[ks] = *(const f32x4*)(cptr + ks * 32 + 4);
    }

    // ---- cvt + ds_write A (waits only the A loads; c stays in flight) ----
    #pragma unroll
    for (int u = 0; u < kNT; ++u) {
        half8 h;
        h[0] = (_Float16)a0[u][0]; h[1] = (_Float16)a0[u][1];
        h[2] = (_Float16)a0[u][2]; h[3] = (_Float16)a0[u][3];
        h[4] = (_Float16)a1[u][0]; h[5] = (_Float16)a1[u][1];
        h[6] = (_Float16)a1[u][2]; h[7] = (_Float16)a1[u][3];
        ((half8*)As)[u * 512 + tid] = h;
    }

    // ---- convert c -> f16 A-operand frags (frees 32 VGPR) ----
    half8 af[kKS];
    #pragma unroll
    for (int ks = 0; ks < kKS; ++ks) {
        af[ks][0] = (_Float16)cv0[ks][0]; af[ks][1] = (_Float16)cv0[ks][1];
        af[ks][2] = (_Float16)cv0[ks][2]; af[ks][3] = (_Float16)cv0[ks][3];
        af[ks][4] = (_Float16)cv1[ks][0]; af[ks][5] = (_Float16)cv1[ks][1];
        af[ks][6] = (_Float16)cv1[ks][2]; af[ks][7] = (_Float16)cv1[ks][3];
    }

    // ---- bias preloads ----
    const float* __restrict__ brow = Bst + (size_t)t * kN;
    float bvs[kNT];
    #pragma unroll
    for (int nt = 0; nt < kNT; ++nt) bvs[nt] = brow[nt * 16 + lo16];
    float fv[4];
    #pragma unroll
    for (int r = 0; r < 4; ++r) fv[r] = f[m0 + (hi4 << 2) + r];

    __syncthreads();   // LDS staged; all loads drained

    // ---- nt-outer compute with interleaved stores ----
    const half8* __restrict__ Bs = (const half8*)As;
    float* __restrict__ obase = out + (size_t)(m0 + (hi4 << 2)) * kN + lo16;

    #pragma unroll
    for (int nt = 0; nt < kNT; ++nt) {
        f32x4 acc = (f32x4){0.f, 0.f, 0.f, 0.f};
        #pragma unroll
        for (int ks = 0; ks < kKS; ++ks) {
            half8 bf = Bs[(nt * kKS + ks) * 64 + l];
            acc = __builtin_amdgcn_mfma_f32_16x16x32_f16(af[ks], bf, acc, 0, 0, 0);
        }
        #pragma unroll
        for (int r = 0; r < 4; ++r)
            obase[(size_t)r * kN + nt * 16] = acc[r] + bvs[nt] * fv[r];
    }
}

extern "C" void kernel_launch(void* const* d_in, const int* in_sizes, int n_in,
                              void* d_out, int out_size, void* d_ws, size_t ws_size,
                              hipStream_t stream) {
    const float* c   = (const float*)d_in[0];
    const float* f   = (const float*)d_in[1];
    const float* A   = (const float*)d_in[2];
    const float* B   = (const float*)d_in[3];
    const int*   t   = (const int*)d_in[4];
    float* out = (float*)d_out;

    const int batch = in_sizes[0] / kN;   // 32768

    hipFuncSetAttribute((const void*)hippo_fused,
                        hipFuncAttributeMaxDynamicSharedMemorySize,
                        (int)kLDS);

    hipLaunchKernelGGL(hippo_fused, dim3(batch / kBM), dim3(512), kLDS, stream,
                       c, f, A, B, t, out);
}